// Round 1
// baseline (3087.891 us; speedup 1.0000x reference)
//
#include <hip/hip_runtime.h>
#include <hip/hip_bf16.h>
#include <math.h>

#define T_TOK 2048
#define D_DIM 1024
#define F_DIM 4096
#define E_NUM 8
#define LDA 40   // LDS row stride in shorts (80B, 16B-aligned, conflict-reducing)

typedef __attribute__((ext_vector_type(8))) short short8;
typedef __attribute__((ext_vector_type(4))) short short4v;
typedef __attribute__((ext_vector_type(4))) float floatx4;

__device__ __forceinline__ short f2bf(float f) {
  union { float f; unsigned u; } v; v.f = f;
  unsigned r = v.u + 0x7fffu + ((v.u >> 16) & 1u);  // RNE
  return (short)(r >> 16);
}

// ---------------- Router: logits (fp32), top-2, renorm, build expert lists ----------------
__global__ __launch_bounds__(256) void router_kernel(
    const float* __restrict__ x, const float* __restrict__ wr,
    int* __restrict__ counts, int* __restrict__ slot_sid, float* __restrict__ slot_w) {
  int lane = threadIdx.x & 63;
  int wave = threadIdx.x >> 6;
  int t = blockIdx.x * 4 + wave;
  const float* xr = x + (size_t)t * D_DIM;
  float acc[8];
#pragma unroll
  for (int e = 0; e < 8; e++) acc[e] = 0.f;
#pragma unroll
  for (int i = 0; i < 16; i++) {
    int d = i * 64 + lane;
    float xv = xr[d];
    const float* w = wr + d * 8;
    float4 w0 = *(const float4*)(w);
    float4 w1 = *(const float4*)(w + 4);
    acc[0] += xv * w0.x; acc[1] += xv * w0.y;
    acc[2] += xv * w0.z; acc[3] += xv * w0.w;
    acc[4] += xv * w1.x; acc[5] += xv * w1.y;
    acc[6] += xv * w1.z; acc[7] += xv * w1.w;
  }
#pragma unroll
  for (int off = 32; off > 0; off >>= 1) {
#pragma unroll
    for (int e = 0; e < 8; e++) acc[e] += __shfl_xor(acc[e], off, 64);
  }
  if (lane == 0) {
    int e1 = 0; float l1 = acc[0];
#pragma unroll
    for (int e = 1; e < 8; e++) { if (acc[e] > l1) { l1 = acc[e]; e1 = e; } }
    int e2 = -1; float l2 = -3.4e38f;
#pragma unroll
    for (int e = 0; e < 8; e++) { if (e != e1 && acc[e] > l2) { l2 = acc[e]; e2 = e; } }
    // softmax->top2->renorm == softmax over {l1,l2}
    float w1 = 1.f / (1.f + __expf(l2 - l1));
    float w2 = 1.f - w1;
    int p1 = atomicAdd(&counts[e1], 1);
    slot_sid[e1 * T_TOK + p1] = 2 * t;
    slot_w[e1 * T_TOK + p1] = w1;
    int p2 = atomicAdd(&counts[e2], 1);
    slot_sid[e2 * T_TOK + p2] = 2 * t + 1;
    slot_w[e2 * T_TOK + p2] = w2;
  }
}

// ---------------- Fused gate+up GEMM per expert, epilogue silu(g)*u -> H (bf16) ----------------
// grid: e(8) x nt(32) x mt(16); block 256 = 4 waves (2x2), tile 128x128, BK=32
__global__ void gateup_kernel(
    const float* __restrict__ x, const float* __restrict__ Wg, const float* __restrict__ Wu,
    const int* __restrict__ counts, const int* __restrict__ slot_sid,
    short* __restrict__ H) {
  __shared__ short As[128 * LDA];
  __shared__ short Bgs[128 * LDA];
  __shared__ short Bus[128 * LDA];
  __shared__ int s_sid[128];

  int bid = blockIdx.x;
  int mt = bid & 15;
  int nt = (bid >> 4) & 31;
  int e  = bid >> 9;
  int n_e = counts[e];
  if (mt * 128 >= n_e) return;

  int tid = threadIdx.x;
  if (tid < 128) {
    int i = mt * 128 + tid;
    if (i > n_e - 1) i = n_e - 1;       // clamp padded rows (guarded at store)
    s_sid[tid] = slot_sid[e * T_TOK + i];
  }
  __syncthreads();

  // A staging: 4 rows per thread, float4 each
  const float* xrow[4];
  {
    int r0 = tid >> 3;
    int c4 = (tid & 7) * 4;
#pragma unroll
    for (int rr = 0; rr < 4; rr++) {
      int tok = s_sid[rr * 32 + r0] >> 1;
      xrow[rr] = x + (size_t)tok * D_DIM + c4;
    }
  }
  // B staging: thread covers fixed f-col, 16 k values (transpose into [n][k])
  int bn = tid & 127;
  int bkg = tid >> 7;
  const float* wg_p = Wg + (size_t)e * D_DIM * F_DIM + (size_t)(bkg * 16) * F_DIM + nt * 128 + bn;
  const float* wu_p = Wu + (size_t)e * D_DIM * F_DIM + (size_t)(bkg * 16) * F_DIM + nt * 128 + bn;

  int lane = tid & 63;
  int wave = tid >> 6;
  int wm = wave >> 1, wn = wave & 1;
  int r16 = lane & 15;
  int q = lane >> 4;

  floatx4 zero4 = {0.f, 0.f, 0.f, 0.f};
  floatx4 accg[4][4], accu[4][4];
#pragma unroll
  for (int a = 0; a < 4; a++)
#pragma unroll
    for (int b = 0; b < 4; b++) { accg[a][b] = zero4; accu[a][b] = zero4; }

  for (int kb = 0; kb < D_DIM / 32; kb++) {
    int k0 = kb * 32;
    float4 av[4];
#pragma unroll
    for (int rr = 0; rr < 4; rr++) av[rr] = *(const float4*)(xrow[rr] + k0);
    float gbuf[16], ubuf[16];
    const float* gp = wg_p + (size_t)k0 * F_DIM;
    const float* up = wu_p + (size_t)k0 * F_DIM;
#pragma unroll
    for (int kk = 0; kk < 16; kk++) {
      gbuf[kk] = gp[(size_t)kk * F_DIM];
      ubuf[kk] = up[(size_t)kk * F_DIM];
    }
    __syncthreads();
    {
      int r0 = tid >> 3;
      int c4 = (tid & 7) * 4;
#pragma unroll
      for (int rr = 0; rr < 4; rr++) {
        short4v sv;
        sv[0] = f2bf(av[rr].x); sv[1] = f2bf(av[rr].y);
        sv[2] = f2bf(av[rr].z); sv[3] = f2bf(av[rr].w);
        *(short4v*)&As[(rr * 32 + r0) * LDA + c4] = sv;
      }
      short8 g0, g1, u0, u1;
#pragma unroll
      for (int kk = 0; kk < 8; kk++) {
        g0[kk] = f2bf(gbuf[kk]); g1[kk] = f2bf(gbuf[kk + 8]);
        u0[kk] = f2bf(ubuf[kk]); u1[kk] = f2bf(ubuf[kk + 8]);
      }
      *(short8*)&Bgs[bn * LDA + bkg * 16]     = g0;
      *(short8*)&Bgs[bn * LDA + bkg * 16 + 8] = g1;
      *(short8*)&Bus[bn * LDA + bkg * 16]     = u0;
      *(short8*)&Bus[bn * LDA + bkg * 16 + 8] = u1;
    }
    __syncthreads();
    short8 af[4], bgf[4], buf_[4];
#pragma unroll
    for (int f = 0; f < 4; f++) {
      af[f]   = *(const short8*)&As[(wm * 64 + f * 16 + r16) * LDA + q * 8];
      bgf[f]  = *(const short8*)&Bgs[(wn * 64 + f * 16 + r16) * LDA + q * 8];
      buf_[f] = *(const short8*)&Bus[(wn * 64 + f * 16 + r16) * LDA + q * 8];
    }
#pragma unroll
    for (int fm = 0; fm < 4; fm++)
#pragma unroll
      for (int fn = 0; fn < 4; fn++) {
        accg[fm][fn] = __builtin_amdgcn_mfma_f32_16x16x32_bf16(af[fm], bgf[fn],  accg[fm][fn], 0, 0, 0);
        accu[fm][fn] = __builtin_amdgcn_mfma_f32_16x16x32_bf16(af[fm], buf_[fn], accu[fm][fn], 0, 0, 0);
      }
  }

  // epilogue: h = silu(g)*u -> H[sid][f] bf16
#pragma unroll
  for (int fm = 0; fm < 4; fm++) {
#pragma unroll
    for (int reg = 0; reg < 4; reg++) {
      int row = wm * 64 + fm * 16 + q * 4 + reg;
      int i = mt * 128 + row;
      if (i < n_e) {
        int sid = s_sid[row];
        size_t hb = (size_t)sid * F_DIM + nt * 128 + wn * 64 + r16;
#pragma unroll
        for (int fn = 0; fn < 4; fn++) {
          float g = accg[fm][fn][reg];
          float u = accu[fm][fn][reg];
          float h = g * u / (1.f + __expf(-g));
          H[hb + fn * 16] = f2bf(h);
        }
      }
    }
  }
}

// ---------------- Down GEMM per expert: Y[sid][d] = w * (H_row @ Wd_e) ----------------
// grid: e(8) x nt(8) x mt(16); tile 128x128, BK=32, K=4096
__global__ void down_kernel(
    const short* __restrict__ H, const float* __restrict__ Wd,
    const int* __restrict__ counts, const int* __restrict__ slot_sid,
    const float* __restrict__ slot_w, float* __restrict__ Y) {
  __shared__ short As[128 * LDA];
  __shared__ short Bs[128 * LDA];
  __shared__ int s_sid[128];
  __shared__ float s_w[128];

  int bid = blockIdx.x;
  int mt = bid & 15;
  int nt = (bid >> 4) & 7;
  int e  = bid >> 7;
  int n_e = counts[e];
  if (mt * 128 >= n_e) return;

  int tid = threadIdx.x;
  if (tid < 128) {
    int i = mt * 128 + tid;
    if (i > n_e - 1) i = n_e - 1;
    s_sid[tid] = slot_sid[e * T_TOK + i];
    s_w[tid]   = slot_w[e * T_TOK + i];
  }
  __syncthreads();

  const short* hrow[2];
  {
    int r0 = tid >> 2;          // 0..63
    int c8 = (tid & 3) * 8;     // 0,8,16,24
#pragma unroll
    for (int p = 0; p < 2; p++) {
      int sid = s_sid[p * 64 + r0];
      hrow[p] = H + (size_t)sid * F_DIM + c8;
    }
  }
  int bn = tid & 127;
  int bkg = tid >> 7;
  const float* wd_p = Wd + (size_t)e * F_DIM * D_DIM + (size_t)(bkg * 16) * D_DIM + nt * 128 + bn;

  int lane = tid & 63, wave = tid >> 6;
  int wm = wave >> 1, wn = wave & 1;
  int r16 = lane & 15, q = lane >> 4;

  floatx4 zero4 = {0.f, 0.f, 0.f, 0.f};
  floatx4 acc[4][4];
#pragma unroll
  for (int a = 0; a < 4; a++)
#pragma unroll
    for (int b = 0; b < 4; b++) acc[a][b] = zero4;

  for (int kb = 0; kb < F_DIM / 32; kb++) {
    int k0 = kb * 32;
    short8 av0 = *(const short8*)(hrow[0] + k0);
    short8 av1 = *(const short8*)(hrow[1] + k0);
    float bbuf[16];
    const float* bp = wd_p + (size_t)k0 * D_DIM;
#pragma unroll
    for (int kk = 0; kk < 16; kk++) bbuf[kk] = bp[(size_t)kk * D_DIM];
    __syncthreads();
    {
      int r0 = tid >> 2, c8 = (tid & 3) * 8;
      *(short8*)&As[r0 * LDA + c8]        = av0;
      *(short8*)&As[(64 + r0) * LDA + c8] = av1;
      short8 b0, b1;
#pragma unroll
      for (int kk = 0; kk < 8; kk++) { b0[kk] = f2bf(bbuf[kk]); b1[kk] = f2bf(bbuf[kk + 8]); }
      *(short8*)&Bs[bn * LDA + bkg * 16]     = b0;
      *(short8*)&Bs[bn * LDA + bkg * 16 + 8] = b1;
    }
    __syncthreads();
    short8 af[4], bf[4];
#pragma unroll
    for (int f = 0; f < 4; f++) {
      af[f] = *(const short8*)&As[(wm * 64 + f * 16 + r16) * LDA + q * 8];
      bf[f] = *(const short8*)&Bs[(wn * 64 + f * 16 + r16) * LDA + q * 8];
    }
#pragma unroll
    for (int fm = 0; fm < 4; fm++)
#pragma unroll
      for (int fn = 0; fn < 4; fn++)
        acc[fm][fn] = __builtin_amdgcn_mfma_f32_16x16x32_bf16(af[fm], bf[fn], acc[fm][fn], 0, 0, 0);
  }

#pragma unroll
  for (int fm = 0; fm < 4; fm++) {
#pragma unroll
    for (int reg = 0; reg < 4; reg++) {
      int row = wm * 64 + fm * 16 + q * 4 + reg;
      int i = mt * 128 + row;
      if (i < n_e) {
        int sid = s_sid[row];
        float w = s_w[row];
        size_t yb = (size_t)sid * D_DIM + nt * 128 + wn * 64 + r16;
#pragma unroll
        for (int fn = 0; fn < 4; fn++)
          Y[yb + fn * 16] = acc[fm][fn][reg] * w;
      }
    }
  }
}

// ---------------- Combine: out[t] = Y[2t] + Y[2t+1] ----------------
__global__ __launch_bounds__(256) void combine_kernel(
    const float* __restrict__ Y, float* __restrict__ out) {
  int idx = blockIdx.x * 256 + threadIdx.x;   // over T*D/4
  int t = idx >> 8;
  int j = idx & 255;
  const float4* Yv = (const float4*)Y;
  float4 a = Yv[(size_t)(2 * t) * 256 + j];
  float4 b = Yv[(size_t)(2 * t + 1) * 256 + j];
  float4 r;
  r.x = a.x + b.x; r.y = a.y + b.y; r.z = a.z + b.z; r.w = a.w + b.w;
  ((float4*)out)[idx] = r;
}

extern "C" void kernel_launch(void* const* d_in, const int* in_sizes, int n_in,
                              void* d_out, int out_size, void* d_ws, size_t ws_size,
                              hipStream_t stream) {
  const float* x  = (const float*)d_in[0];
  const float* wr = (const float*)d_in[1];
  const float* Wg = (const float*)d_in[2];
  const float* Wu = (const float*)d_in[3];
  const float* Wd = (const float*)d_in[4];
  float* out = (float*)d_out;

  char* ws = (char*)d_ws;
  int*   counts   = (int*)(ws);                         // 32 B
  int*   slot_sid = (int*)(ws + 1024);                  // 64 KB
  float* slot_w   = (float*)(ws + 1024 + 65536);        // 64 KB
  short* H        = (short*)(ws + 262144);              // 32 MB (4096 x 4096 bf16)
  float* Y        = (float*)(ws + 262144 + 33554432);   // 16 MB (4096 x 1024 f32)

  hipMemsetAsync(counts, 0, E_NUM * sizeof(int), stream);
  router_kernel<<<T_TOK / 4, 256, 0, stream>>>(x, wr, counts, slot_sid, slot_w);
  gateup_kernel<<<E_NUM * 32 * 16, 256, 0, stream>>>(x, Wg, Wu, counts, slot_sid, H);
  down_kernel<<<E_NUM * 8 * 16, 256, 0, stream>>>(H, Wd, counts, slot_sid, slot_w, Y);
  combine_kernel<<<T_TOK * D_DIM / 4 / 256, 256, 0, stream>>>(Y, out);
}

// Round 2
// 2515.371 us; speedup vs baseline: 1.2276x; 1.2276x over previous
//
#include <hip/hip_runtime.h>
#include <hip/hip_bf16.h>
#include <math.h>

#define T_TOK 2048
#define D_DIM 1024
#define F_DIM 4096
#define E_NUM 8

typedef __attribute__((ext_vector_type(8))) short short8;
typedef __attribute__((ext_vector_type(4))) short short4v;
typedef __attribute__((ext_vector_type(4))) float floatx4;

__device__ __forceinline__ short f2bf(float f) {
  union { float f; unsigned u; } v; v.f = f;
  unsigned r = v.u + 0x7fffu + ((v.u >> 16) & 1u);  // RNE
  return (short)(r >> 16);
}

// async global->LDS, 16B per lane. LDS base must be wave-uniform; data for
// lane l lands at lds + l*16 bytes.
__device__ __forceinline__ void gld_lds16(const void* g, void* l) {
  __builtin_amdgcn_global_load_lds(
      (const __attribute__((address_space(1))) unsigned int*)g,
      (__attribute__((address_space(3))) unsigned int*)l, 16, 0, 0);
}

// ---------------- Router (fp32): logits, top-2, renorm, expert slot lists ----------------
__global__ __launch_bounds__(256) void router_kernel(
    const float* __restrict__ x, const float* __restrict__ wr,
    int* __restrict__ counts, int* __restrict__ slot_sid, float* __restrict__ slot_w) {
  int lane = threadIdx.x & 63;
  int wave = threadIdx.x >> 6;
  int t = blockIdx.x * 4 + wave;
  const float* xr = x + (size_t)t * D_DIM;
  float acc[8];
#pragma unroll
  for (int e = 0; e < 8; e++) acc[e] = 0.f;
#pragma unroll
  for (int i = 0; i < 16; i++) {
    int d = i * 64 + lane;
    float xv = xr[d];
    const float* w = wr + d * 8;
    float4 w0 = *(const float4*)(w);
    float4 w1 = *(const float4*)(w + 4);
    acc[0] += xv * w0.x; acc[1] += xv * w0.y;
    acc[2] += xv * w0.z; acc[3] += xv * w0.w;
    acc[4] += xv * w1.x; acc[5] += xv * w1.y;
    acc[6] += xv * w1.z; acc[7] += xv * w1.w;
  }
#pragma unroll
  for (int off = 32; off > 0; off >>= 1) {
#pragma unroll
    for (int e = 0; e < 8; e++) acc[e] += __shfl_xor(acc[e], off, 64);
  }
  if (lane == 0) {
    int e1 = 0; float l1 = acc[0];
#pragma unroll
    for (int e = 1; e < 8; e++) { if (acc[e] > l1) { l1 = acc[e]; e1 = e; } }
    int e2 = -1; float l2 = -3.4e38f;
#pragma unroll
    for (int e = 0; e < 8; e++) { if (e != e1 && acc[e] > l2) { l2 = acc[e]; e2 = e; } }
    float w1 = 1.f / (1.f + __expf(l2 - l1));  // softmax->top2->renorm
    float w2 = 1.f - w1;
    int p1 = atomicAdd(&counts[e1], 1);
    slot_sid[e1 * T_TOK + p1] = 2 * t;
    slot_w[e1 * T_TOK + p1] = w1;
    int p2 = atomicAdd(&counts[e2], 1);
    slot_sid[e2 * T_TOK + p2] = 2 * t + 1;
    slot_w[e2 * T_TOK + p2] = w2;
  }
}

// ---------------- x fp32 -> bf16 ----------------
__global__ __launch_bounds__(256) void cvt_x_kernel(const float* __restrict__ x,
                                                    short* __restrict__ Xb) {
  int i = blockIdx.x * 256 + threadIdx.x;   // float4 index
  float4 v = ((const float4*)x)[i];
  short4v s;
  s[0] = f2bf(v.x); s[1] = f2bf(v.y); s[2] = f2bf(v.z); s[3] = f2bf(v.w);
  ((short4v*)Xb)[i] = s;
}

// ---------------- Transpose+convert: src fp32 [R][C] -> dst bf16 [C][R] per plane ----------------
__global__ __launch_bounds__(256) void transpose_cvt_kernel(
    const float* __restrict__ src, short* __restrict__ dst, int R, int C) {
  __shared__ short tile[64][68];
  int cb = blockIdx.x * 64, rb = blockIdx.y * 64;
  size_t plane = (size_t)blockIdx.z * R * C;
  src += plane; dst += plane;
  int tid = threadIdx.x;
  int r0 = tid >> 4, c4 = (tid & 15) * 4;
#pragma unroll
  for (int i = 0; i < 4; i++) {
    int r = r0 + i * 16;
    float4 v = *(const float4*)&src[(size_t)(rb + r) * C + cb + c4];
    short4v s;
    s[0] = f2bf(v.x); s[1] = f2bf(v.y); s[2] = f2bf(v.z); s[3] = f2bf(v.w);
    *(short4v*)&tile[r][c4] = s;
  }
  __syncthreads();
  int c0 = tid >> 4, r4 = (tid & 15) * 4;
#pragma unroll
  for (int i = 0; i < 4; i++) {
    int c = c0 + i * 16;
    short4v s;
    s[0] = tile[r4][c]; s[1] = tile[r4 + 1][c];
    s[2] = tile[r4 + 2][c]; s[3] = tile[r4 + 3][c];
    *(short4v*)&dst[(size_t)(cb + c) * R + rb + r4] = s;
  }
}

// ---------------- Fused gate+up GEMM (m97-style), epilogue silu(g)*u -> H bf16 ----------------
// tile 128x128, BK=32; A = Xb rows gathered by slot; B = WgT/WuT [E][F][D] bf16
__global__ void gateup_kernel(
    const short* __restrict__ Xb, const short* __restrict__ WgT, const short* __restrict__ WuT,
    const int* __restrict__ counts, const int* __restrict__ slot_sid,
    short* __restrict__ H) {
  __shared__ short smem[3 * 4096];     // As | Bg | Bu (8KB each); epilogue slab reuses front
  short* As = smem;
  short* Bg = smem + 4096;
  short* Bu = smem + 8192;
  __shared__ int s_sid[128];

  int bid = blockIdx.x;
  int mt = bid & 15;
  int nt = (bid >> 4) & 31;
  int e  = bid >> 9;
  int n_e = counts[e];
  if (mt * 128 >= n_e) return;

  int tid = threadIdx.x;
  if (tid < 128) {
    int i = mt * 128 + tid;
    if (i > n_e - 1) i = n_e - 1;      // clamp; guarded at store
    s_sid[tid] = slot_sid[e * T_TOK + i];
  }
  __syncthreads();

  int lane = tid & 63;
  int w = tid >> 6;
  int wm = w >> 1, wn = w & 1;
  int r16 = lane & 15, q = lane >> 4;

  // staging: wave w covers rows [w*32, w*32+32), 2 instrs of 16 rows
  int srow0 = w * 32 + (lane >> 2);
  int srow1 = srow0 + 16;
  int kc = (lane & 3) * 8;             // shorts within 32-k row
  const short* aP0 = Xb + (size_t)(s_sid[srow0] >> 1) * D_DIM + kc;
  const short* aP1 = Xb + (size_t)(s_sid[srow1] >> 1) * D_DIM + kc;
  size_t wbase = (size_t)e * F_DIM * D_DIM + (size_t)(nt * 128) * D_DIM;
  const short* gP0 = WgT + wbase + (size_t)srow0 * D_DIM + kc;
  const short* gP1 = WgT + wbase + (size_t)srow1 * D_DIM + kc;
  const short* uP0 = WuT + wbase + (size_t)srow0 * D_DIM + kc;
  const short* uP1 = WuT + wbase + (size_t)srow1 * D_DIM + kc;
  short* lds0 = (short*)smem + (w * 32) * 32;        // wave-uniform LDS bases
  short* lds1 = (short*)smem + (w * 32 + 16) * 32;

  floatx4 zero4 = {0.f, 0.f, 0.f, 0.f};
  floatx4 accg[4][4], accu[4][4];
#pragma unroll
  for (int a = 0; a < 4; a++)
#pragma unroll
    for (int b = 0; b < 4; b++) { accg[a][b] = zero4; accu[a][b] = zero4; }

  for (int kb = 0; kb < D_DIM / 32; kb++) {
    gld_lds16(aP0, lds0);
    gld_lds16(aP1, lds1);
    gld_lds16(gP0, lds0 + 4096);
    gld_lds16(gP1, lds1 + 4096);
    gld_lds16(uP0, lds0 + 8192);
    gld_lds16(uP1, lds1 + 8192);
    aP0 += 32; aP1 += 32; gP0 += 32; gP1 += 32; uP0 += 32; uP1 += 32;
    __syncthreads();
    short8 af[4], bgf[4], buf_[4];
#pragma unroll
    for (int f = 0; f < 4; f++) {
      af[f]   = *(const short8*)&As[(wm * 64 + f * 16 + r16) * 32 + q * 8];
      bgf[f]  = *(const short8*)&Bg[(wn * 64 + f * 16 + r16) * 32 + q * 8];
      buf_[f] = *(const short8*)&Bu[(wn * 64 + f * 16 + r16) * 32 + q * 8];
    }
#pragma unroll
    for (int fm = 0; fm < 4; fm++)
#pragma unroll
      for (int fn = 0; fn < 4; fn++) {
        accg[fm][fn] = __builtin_amdgcn_mfma_f32_16x16x32_bf16(af[fm], bgf[fn],  accg[fm][fn], 0, 0, 0);
        accu[fm][fn] = __builtin_amdgcn_mfma_f32_16x16x32_bf16(af[fm], buf_[fn], accu[fm][fn], 0, 0, 0);
      }
    __syncthreads();
  }

  // epilogue via LDS slab (stride 136 shorts = 272B, 16B-aligned rows) -> 16B stores
  short* slab = smem;
#pragma unroll
  for (int fm = 0; fm < 4; fm++) {
#pragma unroll
    for (int reg = 0; reg < 4; reg++) {
      int rowl = wm * 16 + q * 4 + reg;
#pragma unroll
      for (int fn = 0; fn < 4; fn++) {
        float g = accg[fm][fn][reg];
        float u = accu[fm][fn][reg];
        float h = g * u / (1.f + __expf(-g));
        slab[rowl * 136 + wn * 64 + fn * 16 + r16] = f2bf(h);
      }
    }
    __syncthreads();
    int rl = tid >> 3, cs = (tid & 7) * 16;
    int grow = (rl >> 4) * 64 + fm * 16 + (rl & 15);
    if (mt * 128 + grow < n_e) {
      int sid = s_sid[grow];
      short8 v0 = *(const short8*)&slab[rl * 136 + cs];
      short8 v1 = *(const short8*)&slab[rl * 136 + cs + 8];
      short* hp = H + (size_t)sid * F_DIM + nt * 128 + cs;
      *(short8*)&hp[0] = v0;
      *(short8*)&hp[8] = v1;
    }
    __syncthreads();
  }
}

// ---------------- Down GEMM, split-K=4: Y4[sk][sid][d] = w * (H[sid][ks..] @ WdT_e) ----------------
__global__ void down_kernel(
    const short* __restrict__ H, const short* __restrict__ WdT,
    const int* __restrict__ counts, const int* __restrict__ slot_sid,
    const float* __restrict__ slot_w, float* __restrict__ Y) {
  __shared__ short smem[2 * 4096];     // As | Bs
  short* As = smem;
  short* Bs = smem + 4096;
  __shared__ int s_sid[128];
  __shared__ float s_w[128];

  int bid = blockIdx.x;
  int mt = bid & 15;
  int sk = (bid >> 4) & 3;
  int nt = (bid >> 6) & 7;
  int e  = bid >> 9;
  int n_e = counts[e];
  if (mt * 128 >= n_e) return;

  int tid = threadIdx.x;
  if (tid < 128) {
    int i = mt * 128 + tid;
    if (i > n_e - 1) i = n_e - 1;
    s_sid[tid] = slot_sid[e * T_TOK + i];
    s_w[tid]   = slot_w[e * T_TOK + i];
  }
  __syncthreads();

  int lane = tid & 63;
  int w = tid >> 6;
  int wm = w >> 1, wn = w & 1;
  int r16 = lane & 15, q = lane >> 4;

  int srow0 = w * 32 + (lane >> 2);
  int srow1 = srow0 + 16;
  int kc = (lane & 3) * 8;
  int ks = sk * (F_DIM / 4);
  const short* aP0 = H + (size_t)s_sid[srow0] * F_DIM + ks + kc;
  const short* aP1 = H + (size_t)s_sid[srow1] * F_DIM + ks + kc;
  size_t wbase = ((size_t)e * D_DIM + nt * 128) * F_DIM;
  const short* bP0 = WdT + wbase + (size_t)srow0 * F_DIM + ks + kc;
  const short* bP1 = WdT + wbase + (size_t)srow1 * F_DIM + ks + kc;
  short* lds0 = smem + (w * 32) * 32;
  short* lds1 = smem + (w * 32 + 16) * 32;

  floatx4 zero4 = {0.f, 0.f, 0.f, 0.f};
  floatx4 acc[4][4];
#pragma unroll
  for (int a = 0; a < 4; a++)
#pragma unroll
    for (int b = 0; b < 4; b++) acc[a][b] = zero4;

  for (int kb = 0; kb < (F_DIM / 4) / 32; kb++) {
    gld_lds16(aP0, lds0);
    gld_lds16(aP1, lds1);
    gld_lds16(bP0, lds0 + 4096);
    gld_lds16(bP1, lds1 + 4096);
    aP0 += 32; aP1 += 32; bP0 += 32; bP1 += 32;
    __syncthreads();
    short8 af[4], bf[4];
#pragma unroll
    for (int f = 0; f < 4; f++) {
      af[f] = *(const short8*)&As[(wm * 64 + f * 16 + r16) * 32 + q * 8];
      bf[f] = *(const short8*)&Bs[(wn * 64 + f * 16 + r16) * 32 + q * 8];
    }
#pragma unroll
    for (int fm = 0; fm < 4; fm++)
#pragma unroll
      for (int fn = 0; fn < 4; fn++)
        acc[fm][fn] = __builtin_amdgcn_mfma_f32_16x16x32_bf16(af[fm], bf[fn], acc[fm][fn], 0, 0, 0);
    __syncthreads();
  }

#pragma unroll
  for (int fm = 0; fm < 4; fm++) {
#pragma unroll
    for (int reg = 0; reg < 4; reg++) {
      int row = wm * 64 + fm * 16 + q * 4 + reg;
      int i = mt * 128 + row;
      if (i < n_e) {
        int sid = s_sid[row];
        float wgt = s_w[row];
        float* yp = Y + ((size_t)sk * (T_TOK * 2) + sid) * D_DIM + nt * 128 + wn * 64 + r16;
#pragma unroll
        for (int fn = 0; fn < 4; fn++)
          yp[fn * 16] = acc[fm][fn][reg] * wgt;
      }
    }
  }
}

// ---------------- Combine: out[t] = sum over sk, k of Y4[sk][2t+k] ----------------
__global__ __launch_bounds__(256) void combine_kernel(
    const float* __restrict__ Y, float* __restrict__ out) {
  int idx = blockIdx.x * 256 + threadIdx.x;   // float4 index over T*D/4
  int t = idx >> 8;
  int j = idx & 255;
  const floatx4* Yv = (const floatx4*)Y;
  floatx4 s = {0.f, 0.f, 0.f, 0.f};
#pragma unroll
  for (int sk = 0; sk < 4; sk++) {
    s += Yv[((size_t)sk * (T_TOK * 2) + 2 * t) * 256 + j];
    s += Yv[((size_t)sk * (T_TOK * 2) + 2 * t + 1) * 256 + j];
  }
  ((floatx4*)out)[idx] = s;
}

extern "C" void kernel_launch(void* const* d_in, const int* in_sizes, int n_in,
                              void* d_out, int out_size, void* d_ws, size_t ws_size,
                              hipStream_t stream) {
  const float* x  = (const float*)d_in[0];
  const float* wr = (const float*)d_in[1];
  const float* Wg = (const float*)d_in[2];
  const float* Wu = (const float*)d_in[3];
  const float* Wd = (const float*)d_in[4];
  float* out = (float*)d_out;

  char* ws = (char*)d_ws;
  int*   counts   = (int*)(ws);                          // 32 B
  int*   slot_sid = (int*)(ws + 4096);                   // 64 KB
  float* slot_w   = (float*)(ws + 4096 + 65536);         // 64 KB
  short* Xb       = (short*)(ws + 0x40000);              // 4 MB
  short* H        = (short*)(ws + 0x800000);             // 32 MB
  short* WgT      = (short*)(ws + 0x2800000);            // 64 MB (later: WdT)
  short* WuT      = (short*)(ws + 0x6800000);            // 64 MB (later: Y4)
  short* WdT      = WgT;                                 // reuse after gateup
  float* Y4       = (float*)WuT;                         // reuse after gateup

  hipMemsetAsync(counts, 0, E_NUM * sizeof(int), stream);
  router_kernel<<<T_TOK / 4, 256, 0, stream>>>(x, wr, counts, slot_sid, slot_w);
  cvt_x_kernel<<<T_TOK * D_DIM / 4 / 256, 256, 0, stream>>>(x, Xb);
  // WgT/WuT: [E][D][F] fp32 -> [E][F][D] bf16
  transpose_cvt_kernel<<<dim3(F_DIM / 64, D_DIM / 64, E_NUM), 256, 0, stream>>>(Wg, WgT, D_DIM, F_DIM);
  transpose_cvt_kernel<<<dim3(F_DIM / 64, D_DIM / 64, E_NUM), 256, 0, stream>>>(Wu, WuT, D_DIM, F_DIM);
  gateup_kernel<<<E_NUM * 32 * 16, 256, 0, stream>>>(Xb, WgT, WuT, counts, slot_sid, H);
  // WdT: [E][F][D] fp32 -> [E][D][F] bf16 (overwrites WgT region — gateup done)
  transpose_cvt_kernel<<<dim3(D_DIM / 64, F_DIM / 64, E_NUM), 256, 0, stream>>>(Wd, WdT, F_DIM, D_DIM);
  down_kernel<<<E_NUM * 8 * 4 * 16, 256, 0, stream>>>(H, WdT, counts, slot_sid, slot_w, Y4);
  combine_kernel<<<T_TOK * D_DIM / 4 / 256, 256, 0, stream>>>(Y4, out);
}

// Round 3
// 926.118 us; speedup vs baseline: 3.3342x; 2.7160x over previous
//
#include <hip/hip_runtime.h>
#include <hip/hip_bf16.h>
#include <math.h>

#define T_TOK 2048
#define D_DIM 1024
#define F_DIM 4096
#define E_NUM 8

typedef __attribute__((ext_vector_type(8))) short short8;
typedef __attribute__((ext_vector_type(4))) short short4v;
typedef __attribute__((ext_vector_type(4))) float floatx4;

__device__ __forceinline__ short f2bf(float f) {
  union { float f; unsigned u; } v; v.f = f;
  unsigned r = v.u + 0x7fffu + ((v.u >> 16) & 1u);  // RNE
  return (short)(r >> 16);
}

// async global->LDS, 16B per lane. LDS base must be wave-uniform; data for
// lane l lands at lds + l*16 bytes.
__device__ __forceinline__ void gld_lds16(const void* g, void* l) {
  __builtin_amdgcn_global_load_lds(
      (const __attribute__((address_space(1))) unsigned int*)g,
      (__attribute__((address_space(3))) unsigned int*)l, 16, 0, 0);
}

// ---------------- Router (fp32): logits, top-2, renorm, expert slot lists ----------------
__global__ __launch_bounds__(256) void router_kernel(
    const float* __restrict__ x, const float* __restrict__ wr,
    int* __restrict__ counts, int* __restrict__ slot_sid, float* __restrict__ slot_w) {
  int lane = threadIdx.x & 63;
  int wave = threadIdx.x >> 6;
  int t = blockIdx.x * 4 + wave;
  const float* xr = x + (size_t)t * D_DIM;
  float acc[8];
#pragma unroll
  for (int e = 0; e < 8; e++) acc[e] = 0.f;
#pragma unroll
  for (int i = 0; i < 16; i++) {
    int d = i * 64 + lane;
    float xv = xr[d];
    const float* w = wr + d * 8;
    float4 w0 = *(const float4*)(w);
    float4 w1 = *(const float4*)(w + 4);
    acc[0] += xv * w0.x; acc[1] += xv * w0.y;
    acc[2] += xv * w0.z; acc[3] += xv * w0.w;
    acc[4] += xv * w1.x; acc[5] += xv * w1.y;
    acc[6] += xv * w1.z; acc[7] += xv * w1.w;
  }
#pragma unroll
  for (int off = 32; off > 0; off >>= 1) {
#pragma unroll
    for (int e = 0; e < 8; e++) acc[e] += __shfl_xor(acc[e], off, 64);
  }
  if (lane == 0) {
    int e1 = 0; float l1 = acc[0];
#pragma unroll
    for (int e = 1; e < 8; e++) { if (acc[e] > l1) { l1 = acc[e]; e1 = e; } }
    int e2 = -1; float l2 = -3.4e38f;
#pragma unroll
    for (int e = 0; e < 8; e++) { if (e != e1 && acc[e] > l2) { l2 = acc[e]; e2 = e; } }
    float w1 = 1.f / (1.f + __expf(l2 - l1));  // softmax->top2->renorm
    float w2 = 1.f - w1;
    int p1 = atomicAdd(&counts[e1], 1);
    slot_sid[e1 * T_TOK + p1] = 2 * t;
    slot_w[e1 * T_TOK + p1] = w1;
    int p2 = atomicAdd(&counts[e2], 1);
    slot_sid[e2 * T_TOK + p2] = 2 * t + 1;
    slot_w[e2 * T_TOK + p2] = w2;
  }
}

// ---------------- x fp32 -> bf16 ----------------
__global__ __launch_bounds__(256) void cvt_x_kernel(const float* __restrict__ x,
                                                    short* __restrict__ Xb) {
  int i = blockIdx.x * 256 + threadIdx.x;   // float4 index
  float4 v = ((const float4*)x)[i];
  short4v s;
  s[0] = f2bf(v.x); s[1] = f2bf(v.y); s[2] = f2bf(v.z); s[3] = f2bf(v.w);
  ((short4v*)Xb)[i] = s;
}

// ---------------- Transpose+convert: src fp32 [R][C] -> dst bf16 [C][R] per plane ----------------
__global__ __launch_bounds__(256) void transpose_cvt_kernel(
    const float* __restrict__ src, short* __restrict__ dst, int R, int C) {
  __shared__ short tile[64][68];
  int cb = blockIdx.x * 64, rb = blockIdx.y * 64;
  size_t plane = (size_t)blockIdx.z * R * C;
  src += plane; dst += plane;
  int tid = threadIdx.x;
  int r0 = tid >> 4, c4 = (tid & 15) * 4;
#pragma unroll
  for (int i = 0; i < 4; i++) {
    int r = r0 + i * 16;
    float4 v = *(const float4*)&src[(size_t)(rb + r) * C + cb + c4];
    short4v s;
    s[0] = f2bf(v.x); s[1] = f2bf(v.y); s[2] = f2bf(v.z); s[3] = f2bf(v.w);
    *(short4v*)&tile[r][c4] = s;
  }
  __syncthreads();
  int c0 = tid >> 4, r4 = (tid & 15) * 4;
#pragma unroll
  for (int i = 0; i < 4; i++) {
    int c = c0 + i * 16;
    short4v s;
    s[0] = tile[r4][c]; s[1] = tile[r4 + 1][c];
    s[2] = tile[r4 + 2][c]; s[3] = tile[r4 + 3][c];
    *(short4v*)&dst[(size_t)(cb + c) * R + rb + r4] = s;
  }
}

// ---------------- Fused gate+up GEMM (m97-style), epilogue silu(g)*u -> H bf16 ----------------
// tile 128x128, BK=32; A = Xb rows gathered by slot; B = WgT/WuT [E][F][D] bf16
// __launch_bounds__(256,2): VGPR budget 256/lane — accg+accu(128) + frags(48) +
// addressing must NOT spill (R2 pathology: default occupancy target capped at
// 64 VGPR -> 2 GB scratch spill traffic, kernel bound on phantom writes).
__global__ __launch_bounds__(256, 2) void gateup_kernel(
    const short* __restrict__ Xb, const short* __restrict__ WgT, const short* __restrict__ WuT,
    const int* __restrict__ counts, const int* __restrict__ slot_sid,
    short* __restrict__ H) {
  __shared__ short smem[3 * 4096];     // As | Bg | Bu (8KB each); epilogue slab reuses front
  short* As = smem;
  short* Bg = smem + 4096;
  short* Bu = smem + 8192;
  __shared__ int s_sid[128];

  int bid = blockIdx.x;
  int mt = bid & 15;
  int nt = (bid >> 4) & 31;
  int e  = bid >> 9;
  int n_e = counts[e];
  if (mt * 128 >= n_e) return;

  int tid = threadIdx.x;
  if (tid < 128) {
    int i = mt * 128 + tid;
    if (i > n_e - 1) i = n_e - 1;      // clamp; guarded at store
    s_sid[tid] = slot_sid[e * T_TOK + i];
  }
  __syncthreads();

  int lane = tid & 63;
  int w = tid >> 6;
  int wm = w >> 1, wn = w & 1;
  int r16 = lane & 15, q = lane >> 4;

  // staging: wave w covers rows [w*32, w*32+32), 2 instrs of 16 rows
  int srow0 = w * 32 + (lane >> 2);
  int srow1 = srow0 + 16;
  int kc = (lane & 3) * 8;             // shorts within 32-k row
  const short* aP0 = Xb + (size_t)(s_sid[srow0] >> 1) * D_DIM + kc;
  const short* aP1 = Xb + (size_t)(s_sid[srow1] >> 1) * D_DIM + kc;
  size_t wbase = (size_t)e * F_DIM * D_DIM + (size_t)(nt * 128) * D_DIM;
  const short* gP0 = WgT + wbase + (size_t)srow0 * D_DIM + kc;
  const short* gP1 = WgT + wbase + (size_t)srow1 * D_DIM + kc;
  const short* uP0 = WuT + wbase + (size_t)srow0 * D_DIM + kc;
  const short* uP1 = WuT + wbase + (size_t)srow1 * D_DIM + kc;
  short* lds0 = (short*)smem + (w * 32) * 32;        // wave-uniform LDS bases
  short* lds1 = (short*)smem + (w * 32 + 16) * 32;

  floatx4 zero4 = {0.f, 0.f, 0.f, 0.f};
  floatx4 accg[4][4], accu[4][4];
#pragma unroll
  for (int a = 0; a < 4; a++)
#pragma unroll
    for (int b = 0; b < 4; b++) { accg[a][b] = zero4; accu[a][b] = zero4; }

  for (int kb = 0; kb < D_DIM / 32; kb++) {
    gld_lds16(aP0, lds0);
    gld_lds16(aP1, lds1);
    gld_lds16(gP0, lds0 + 4096);
    gld_lds16(gP1, lds1 + 4096);
    gld_lds16(uP0, lds0 + 8192);
    gld_lds16(uP1, lds1 + 8192);
    aP0 += 32; aP1 += 32; gP0 += 32; gP1 += 32; uP0 += 32; uP1 += 32;
    __syncthreads();
    short8 af[4], bgf[4], buf_[4];
#pragma unroll
    for (int f = 0; f < 4; f++) {
      af[f]   = *(const short8*)&As[(wm * 64 + f * 16 + r16) * 32 + q * 8];
      bgf[f]  = *(const short8*)&Bg[(wn * 64 + f * 16 + r16) * 32 + q * 8];
      buf_[f] = *(const short8*)&Bu[(wn * 64 + f * 16 + r16) * 32 + q * 8];
    }
#pragma unroll
    for (int fm = 0; fm < 4; fm++)
#pragma unroll
      for (int fn = 0; fn < 4; fn++) {
        accg[fm][fn] = __builtin_amdgcn_mfma_f32_16x16x32_bf16(af[fm], bgf[fn],  accg[fm][fn], 0, 0, 0);
        accu[fm][fn] = __builtin_amdgcn_mfma_f32_16x16x32_bf16(af[fm], buf_[fn], accu[fm][fn], 0, 0, 0);
      }
    __syncthreads();
  }

  // epilogue via LDS slab (stride 136 shorts = 272B, 16B-aligned rows) -> 16B stores
  short* slab = smem;
#pragma unroll
  for (int fm = 0; fm < 4; fm++) {
#pragma unroll
    for (int reg = 0; reg < 4; reg++) {
      int rowl = wm * 16 + q * 4 + reg;
#pragma unroll
      for (int fn = 0; fn < 4; fn++) {
        float g = accg[fm][fn][reg];
        float u = accu[fm][fn][reg];
        float h = g * u / (1.f + __expf(-g));
        slab[rowl * 136 + wn * 64 + fn * 16 + r16] = f2bf(h);
      }
    }
    __syncthreads();
    int rl = tid >> 3, cs = (tid & 7) * 16;
    int grow = (rl >> 4) * 64 + fm * 16 + (rl & 15);
    if (mt * 128 + grow < n_e) {
      int sid = s_sid[grow];
      short8 v0 = *(const short8*)&slab[rl * 136 + cs];
      short8 v1 = *(const short8*)&slab[rl * 136 + cs + 8];
      short* hp = H + (size_t)sid * F_DIM + nt * 128 + cs;
      *(short8*)&hp[0] = v0;
      *(short8*)&hp[8] = v1;
    }
    __syncthreads();
  }
}

// ---------------- Down GEMM, split-K=4: Y4[sk][sid][d] = w * (H[sid][ks..] @ WdT_e) ----------------
// __launch_bounds__(256,3): ~130 regs needed <= 170 budget, 3 blocks/CU.
__global__ __launch_bounds__(256, 3) void down_kernel(
    const short* __restrict__ H, const short* __restrict__ WdT,
    const int* __restrict__ counts, const int* __restrict__ slot_sid,
    const float* __restrict__ slot_w, float* __restrict__ Y) {
  __shared__ short smem[2 * 4096];     // As | Bs
  short* As = smem;
  short* Bs = smem + 4096;
  __shared__ int s_sid[128];
  __shared__ float s_w[128];

  int bid = blockIdx.x;
  int mt = bid & 15;
  int sk = (bid >> 4) & 3;
  int nt = (bid >> 6) & 7;
  int e  = bid >> 9;
  int n_e = counts[e];
  if (mt * 128 >= n_e) return;

  int tid = threadIdx.x;
  if (tid < 128) {
    int i = mt * 128 + tid;
    if (i > n_e - 1) i = n_e - 1;
    s_sid[tid] = slot_sid[e * T_TOK + i];
    s_w[tid]   = slot_w[e * T_TOK + i];
  }
  __syncthreads();

  int lane = tid & 63;
  int w = tid >> 6;
  int wm = w >> 1, wn = w & 1;
  int r16 = lane & 15, q = lane >> 4;

  int srow0 = w * 32 + (lane >> 2);
  int srow1 = srow0 + 16;
  int kc = (lane & 3) * 8;
  int ks = sk * (F_DIM / 4);
  const short* aP0 = H + (size_t)s_sid[srow0] * F_DIM + ks + kc;
  const short* aP1 = H + (size_t)s_sid[srow1] * F_DIM + ks + kc;
  size_t wbase = ((size_t)e * D_DIM + nt * 128) * F_DIM;
  const short* bP0 = WdT + wbase + (size_t)srow0 * F_DIM + ks + kc;
  const short* bP1 = WdT + wbase + (size_t)srow1 * F_DIM + ks + kc;
  short* lds0 = smem + (w * 32) * 32;
  short* lds1 = smem + (w * 32 + 16) * 32;

  floatx4 zero4 = {0.f, 0.f, 0.f, 0.f};
  floatx4 acc[4][4];
#pragma unroll
  for (int a = 0; a < 4; a++)
#pragma unroll
    for (int b = 0; b < 4; b++) acc[a][b] = zero4;

  for (int kb = 0; kb < (F_DIM / 4) / 32; kb++) {
    gld_lds16(aP0, lds0);
    gld_lds16(aP1, lds1);
    gld_lds16(bP0, lds0 + 4096);
    gld_lds16(bP1, lds1 + 4096);
    aP0 += 32; aP1 += 32; bP0 += 32; bP1 += 32;
    __syncthreads();
    short8 af[4], bf[4];
#pragma unroll
    for (int f = 0; f < 4; f++) {
      af[f] = *(const short8*)&As[(wm * 64 + f * 16 + r16) * 32 + q * 8];
      bf[f] = *(const short8*)&Bs[(wn * 64 + f * 16 + r16) * 32 + q * 8];
    }
#pragma unroll
    for (int fm = 0; fm < 4; fm++)
#pragma unroll
      for (int fn = 0; fn < 4; fn++)
        acc[fm][fn] = __builtin_amdgcn_mfma_f32_16x16x32_bf16(af[fm], bf[fn], acc[fm][fn], 0, 0, 0);
    __syncthreads();
  }

#pragma unroll
  for (int fm = 0; fm < 4; fm++) {
#pragma unroll
    for (int reg = 0; reg < 4; reg++) {
      int row = wm * 64 + fm * 16 + q * 4 + reg;
      int i = mt * 128 + row;
      if (i < n_e) {
        int sid = s_sid[row];
        float wgt = s_w[row];
        float* yp = Y + ((size_t)sk * (T_TOK * 2) + sid) * D_DIM + nt * 128 + wn * 64 + r16;
#pragma unroll
        for (int fn = 0; fn < 4; fn++)
          yp[fn * 16] = acc[fm][fn][reg] * wgt;
      }
    }
  }
}

// ---------------- Combine: out[t] = sum over sk, k of Y4[sk][2t+k] ----------------
__global__ __launch_bounds__(256) void combine_kernel(
    const float* __restrict__ Y, float* __restrict__ out) {
  int idx = blockIdx.x * 256 + threadIdx.x;   // float4 index over T*D/4
  int t = idx >> 8;
  int j = idx & 255;
  const floatx4* Yv = (const floatx4*)Y;
  floatx4 s = {0.f, 0.f, 0.f, 0.f};
#pragma unroll
  for (int sk = 0; sk < 4; sk++) {
    s += Yv[((size_t)sk * (T_TOK * 2) + 2 * t) * 256 + j];
    s += Yv[((size_t)sk * (T_TOK * 2) + 2 * t + 1) * 256 + j];
  }
  ((floatx4*)out)[idx] = s;
}

extern "C" void kernel_launch(void* const* d_in, const int* in_sizes, int n_in,
                              void* d_out, int out_size, void* d_ws, size_t ws_size,
                              hipStream_t stream) {
  const float* x  = (const float*)d_in[0];
  const float* wr = (const float*)d_in[1];
  const float* Wg = (const float*)d_in[2];
  const float* Wu = (const float*)d_in[3];
  const float* Wd = (const float*)d_in[4];
  float* out = (float*)d_out;

  char* ws = (char*)d_ws;
  int*   counts   = (int*)(ws);                          // 32 B
  int*   slot_sid = (int*)(ws + 4096);                   // 64 KB
  float* slot_w   = (float*)(ws + 4096 + 65536);         // 64 KB
  short* Xb       = (short*)(ws + 0x40000);              // 4 MB
  short* H        = (short*)(ws + 0x800000);             // 32 MB
  short* WgT      = (short*)(ws + 0x2800000);            // 64 MB (later: WdT)
  short* WuT      = (short*)(ws + 0x6800000);            // 64 MB (later: Y4)
  short* WdT      = WgT;                                 // reuse after gateup
  float* Y4       = (float*)WuT;                         // reuse after gateup

  hipMemsetAsync(counts, 0, E_NUM * sizeof(int), stream);
  router_kernel<<<T_TOK / 4, 256, 0, stream>>>(x, wr, counts, slot_sid, slot_w);
  cvt_x_kernel<<<T_TOK * D_DIM / 4 / 256, 256, 0, stream>>>(x, Xb);
  // WgT/WuT: [E][D][F] fp32 -> [E][F][D] bf16
  transpose_cvt_kernel<<<dim3(F_DIM / 64, D_DIM / 64, E_NUM), 256, 0, stream>>>(Wg, WgT, D_DIM, F_DIM);
  transpose_cvt_kernel<<<dim3(F_DIM / 64, D_DIM / 64, E_NUM), 256, 0, stream>>>(Wu, WuT, D_DIM, F_DIM);
  gateup_kernel<<<E_NUM * 32 * 16, 256, 0, stream>>>(Xb, WgT, WuT, counts, slot_sid, H);
  // WdT: [E][F][D] fp32 -> [E][D][F] bf16 (overwrites WgT region — gateup done)
  transpose_cvt_kernel<<<dim3(D_DIM / 64, F_DIM / 64, E_NUM), 256, 0, stream>>>(Wd, WdT, F_DIM, D_DIM);
  down_kernel<<<E_NUM * 8 * 4 * 16, 256, 0, stream>>>(H, WdT, counts, slot_sid, slot_w, Y4);
  combine_kernel<<<T_TOK * D_DIM / 4 / 256, 256, 0, stream>>>(Y4, out);
}